// Round 1
// baseline (21.220 us; speedup 1.0000x reference)
//
#include <hip/hip_runtime.h>

#define IN_DIM   2048
#define OUT_DIM  16384
#define NTHREADS 256
#define EPS      1e-12f

// out[b][j] = -scale * rnorm_b * WHT2048(x[b])[j & 2047] + bias[j]
// where rnorm_b = rsqrt(max(sum_i x[b][i]^2, EPS)).
// Valid because hadamard = H_16384[:2048,:16384] with H[i][j]=(-1)^popcount(i&j),
// and i<2048 ==> popcount(i&j) depends only on j&2047.
__global__ __launch_bounds__(NTHREADS) void had_fwht_kernel(
    const float* __restrict__ x,
    const float* __restrict__ scale,
    const float* __restrict__ bias,
    float* __restrict__ out)
{
    __shared__ float s[IN_DIM];
    __shared__ float red[NTHREADS / 64];

    const int b   = blockIdx.x;
    const int tid = threadIdx.x;

    // ---- load row as float4, accumulate sum of squares ----
    const float4* xr4 = (const float4*)(x + (size_t)b * IN_DIM);
    float local = 0.f;
#pragma unroll
    for (int i = 0; i < IN_DIM / 4 / NTHREADS; ++i) {   // 2 iters
        const int idx = tid + i * NTHREADS;
        float4 v = xr4[idx];
        ((float4*)s)[idx] = v;
        local = fmaf(v.x, v.x, local);
        local = fmaf(v.y, v.y, local);
        local = fmaf(v.z, v.z, local);
        local = fmaf(v.w, v.w, local);
    }

    // ---- block reduction: 64-lane wave shuffle, then LDS across 4 waves ----
#pragma unroll
    for (int off = 32; off > 0; off >>= 1)
        local += __shfl_down(local, off, 64);
    if ((tid & 63) == 0) red[tid >> 6] = local;
    __syncthreads();                       // also covers the s[] writes above
    const float sumsq = red[0] + red[1] + red[2] + red[3];
    const float c = -scale[0] * rsqrtf(fmaxf(sumsq, EPS));

    // ---- in-place FWHT (natural/Hadamard order), 11 stages ----
#pragma unroll
    for (int d = 1; d < IN_DIM; d <<= 1) {
#pragma unroll
        for (int t = tid; t < IN_DIM / 2; t += NTHREADS) {   // 4 butterflies/thread
            const int i = ((t & ~(d - 1)) << 1) | (t & (d - 1));
            const float a  = s[i];
            const float bb = s[i + d];
            s[i]     = a + bb;
            s[i + d] = a - bb;
        }
        __syncthreads();
    }

    // ---- write 16384 outputs = 8 tiled copies of s, scaled + bias ----
    const float4* bias4 = (const float4*)bias;
    const float4* s4    = (const float4*)s;
    float4* out4        = (float4*)(out + (size_t)b * OUT_DIM);
#pragma unroll
    for (int i = 0; i < OUT_DIM / 4 / NTHREADS; ++i) {  // 16 iters
        const int idx = tid + i * NTHREADS;
        const float4 bv = bias4[idx];
        const float4 sv = s4[idx & (IN_DIM / 4 - 1)];
        float4 o;
        o.x = fmaf(c, sv.x, bv.x);
        o.y = fmaf(c, sv.y, bv.y);
        o.z = fmaf(c, sv.z, bv.z);
        o.w = fmaf(c, sv.w, bv.w);
        out4[idx] = o;
    }
}

extern "C" void kernel_launch(void* const* d_in, const int* in_sizes, int n_in,
                              void* d_out, int out_size, void* d_ws, size_t ws_size,
                              hipStream_t stream) {
    const float* x     = (const float*)d_in[0];
    const float* scale = (const float*)d_in[1];
    const float* bias  = (const float*)d_in[2];
    // d_in[3] (dense hadamard matrix) is not needed: structure exploited in-kernel.
    float* out = (float*)d_out;

    const int batch = in_sizes[0] / IN_DIM;   // 1024
    had_fwht_kernel<<<batch, NTHREADS, 0, stream>>>(x, scale, bias, out);
}

// Round 2
// 18.606 us; speedup vs baseline: 1.1405x; 1.1405x over previous
//
#include <hip/hip_runtime.h>

#define IN_DIM   2048
#define OUT_DIM  16384
#define NT       256
#define EPS      1e-12f

// out[b][j] = -scale * rnorm_b * WHT2048(x[b])[j & 2047] + bias[j]
// (hadamard = H_16384[:2048,:16384], H[i][j]=(-1)^popcount(i&j); i<2048 ==>
//  only j&2047 matters; WHT stages commute so bit order is free.)
//
// Register-blocked FWHT: 8 elements/thread, 11 stages as 4 in-register passes
// (bits 0-2, 3-5, 6-7, 8-10), 3 swizzled LDS shuffle boundaries + 1 linear
// final store. XOR swizzle keeps every LDS boundary at <=2-way bank aliasing.

__device__ __forceinline__ int swz(int e) { return e ^ (((e >> 6) & 7) << 3); }

// butterfly over register index bit m (indices compile-time after unroll)
#define BFLY(m)                                                   \
    _Pragma("unroll")                                             \
    for (int k = 0; k < 8; ++k)                                   \
        if (!(k & (m))) {                                         \
            const float a_ = v[k], b_ = v[k | (m)];               \
            v[k]       = a_ + b_;                                 \
            v[k | (m)] = a_ - b_;                                 \
        }

__global__ __launch_bounds__(NT) void had_fwht_kernel(
    const float* __restrict__ x,
    const float* __restrict__ scale,
    const float* __restrict__ bias,
    float* __restrict__ out)
{
    __shared__ float sA[IN_DIM];     // swizzled shuffle buffer
    __shared__ float sB[IN_DIM];     // linear buffer for output phase
    __shared__ float red[NT / 64];

    const int b = blockIdx.x;
    const int t = threadIdx.x;
    float v[8];

    // ---- load: thread t owns elements e = 8t+k (bits 0-2 = k) ----
    const float4* xr4 = (const float4*)(x + (size_t)b * IN_DIM);
    const float4 a0 = xr4[2 * t];
    const float4 a1 = xr4[2 * t + 1];
    v[0] = a0.x; v[1] = a0.y; v[2] = a0.z; v[3] = a0.w;
    v[4] = a1.x; v[5] = a1.y; v[6] = a1.z; v[7] = a1.w;

    // ---- sum of squares (wave shuffle + LDS across 4 waves) ----
    float local = 0.f;
#pragma unroll
    for (int k = 0; k < 8; ++k) local = fmaf(v[k], v[k], local);
#pragma unroll
    for (int off = 32; off > 0; off >>= 1)
        local += __shfl_down(local, off, 64);
    if ((t & 63) == 0) red[t >> 6] = local;

    // ---- pass 1: stages d=1,2,4 (e bits 0-2) ----
    BFLY(1) BFLY(2) BFLY(4)
    ((float4*)sA)[swz(8 * t)     >> 2] = make_float4(v[0], v[1], v[2], v[3]);
    ((float4*)sA)[swz(8 * t + 4) >> 2] = make_float4(v[4], v[5], v[6], v[7]);
    __syncthreads();

    const float sumsq = red[0] + red[1] + red[2] + red[3];
    const float c = -scale[0] * rsqrtf(fmaxf(sumsq, EPS));

    // ---- pass 2: e = (t&7)|(k<<3)|((t>>3)<<6), stages d=8,16,32 ----
    {
        const int base = (t & 7) | ((t >> 3) << 6);
#pragma unroll
        for (int k = 0; k < 8; ++k) v[k] = sA[swz(base | (k << 3))];
        BFLY(1) BFLY(2) BFLY(4)
#pragma unroll
        for (int k = 0; k < 8; ++k) sA[swz(base | (k << 3))] = v[k];
    }
    __syncthreads();

    // ---- pass 3: e = (t&63)|(k<<6)|((t>>6)<<9), stages d=64,128 (k bits 0-1) ----
    {
        const int base = (t & 63) | ((t >> 6) << 9);
#pragma unroll
        for (int k = 0; k < 8; ++k) v[k] = sA[swz(base | (k << 6))];
        BFLY(1) BFLY(2)
#pragma unroll
        for (int k = 0; k < 8; ++k) sA[swz(base | (k << 6))] = v[k];
    }
    __syncthreads();

    // ---- pass 4: e = t|(k<<8), stages d=256,512,1024; write linear to sB ----
#pragma unroll
    for (int k = 0; k < 8; ++k) v[k] = sA[swz(t | (k << 8))];
    BFLY(1) BFLY(2) BFLY(4)
#pragma unroll
    for (int k = 0; k < 8; ++k) sB[t | (k << 8)] = v[k];
    __syncthreads();

    // ---- output: 8 tiled copies of sB, scaled + bias (fully coalesced) ----
    const float4* bias4 = (const float4*)bias;
    const float4* s4    = (const float4*)sB;
    float4* out4        = (float4*)(out + (size_t)b * OUT_DIM);
#pragma unroll
    for (int i = 0; i < OUT_DIM / 4 / NT; ++i) {   // 16 iters
        const int idx = t + i * NT;
        const float4 bv = bias4[idx];
        const float4 sv = s4[idx & (IN_DIM / 4 - 1)];
        float4 o;
        o.x = fmaf(c, sv.x, bv.x);
        o.y = fmaf(c, sv.y, bv.y);
        o.z = fmaf(c, sv.z, bv.z);
        o.w = fmaf(c, sv.w, bv.w);
        out4[idx] = o;
    }
}

extern "C" void kernel_launch(void* const* d_in, const int* in_sizes, int n_in,
                              void* d_out, int out_size, void* d_ws, size_t ws_size,
                              hipStream_t stream) {
    const float* x     = (const float*)d_in[0];
    const float* scale = (const float*)d_in[1];
    const float* bias  = (const float*)d_in[2];
    // d_in[3] (dense hadamard) unused: structure exploited in-kernel.
    float* out = (float*)d_out;

    const int batch = in_sizes[0] / IN_DIM;   // 1024
    had_fwht_kernel<<<batch, NT, 0, stream>>>(x, scale, bias, out);
}